// Round 8
// baseline (171.039 us; speedup 1.0000x reference)
//
#include <hip/hip_runtime.h>
#include <hip/hip_bf16.h>

// B=8, H=W=1024, N=4096, R=8 -> d=17, patch=289, out (B,4096,578) fp32.
// p1[b,n,j] = image1[b, m1 + j%17 - 8, m0 + j//17 - 8]  (zero-pad OOB)
// normalize each 289-vector: (p - mean) / (std_ddof1 + 1e-4)
//
// R8: make ALL VMEM streaming; move randomness into LDS.
// Evidence: R4 (coalesced gather) neutral, R7 (y-band order) neutral, R5/R6
// (LLC-warm) -25% => random sub-line vector gathers are structurally slow
// regardless of locality; streaming runs at 4.3-6.3 TB/s. So: bin tasks by
// 48x48 image bucket (7744 buckets), one block per bucket streams a 64x64
// (+halo, zero-padded) tile into LDS via coalesced float4, then waves gather
// patches from LDS (stride 65 -> consecutive lanes consecutive banks).

#define IMG_H 1024
#define IMG_W 1024
#define DPATCH 17
#define NPATCH 289
#define RAD 8
#define HW (IMG_H * IMG_W)
#define NTASK 65536            // 8 batches * 4096 pairs * 2 images
#define BKT 48                 // bucket interior
#define TILE 64                // LDS tile = BKT + 2*RAD
#define GB 22                  // buckets per image dim (22*48 >= 1024)
#define NBUCKET (16 * GB * GB) // 7744
#define TSTRIDE 65             // LDS row stride (65%32==1 -> conflict-free column walks)

// d_ws layout (ints): hist[0..8191], starts[8192..16383] (uses NBUCKET+1), tasks[16384..]

__device__ __forceinline__ int task_key(const int* __restrict__ matches, int t) {
    const int pair  = t >> 1;
    const int which = t & 1;
    const int mx = matches[pair * 4 + (which ? 2 : 0)];
    const int my = matches[pair * 4 + (which ? 3 : 1)];
    const int b  = pair >> 12;
    return (((b * 2 + which) * GB) + my / BKT) * GB + mx / BKT;
}

__global__ __launch_bounds__(256) void zero_hist_kernel(int* __restrict__ hist) {
    for (int i = threadIdx.x; i < NBUCKET; i += 256) hist[i] = 0;
}

__global__ __launch_bounds__(256) void hist_kernel(
    const int* __restrict__ matches, int* __restrict__ hist) {
    const int t = blockIdx.x * blockDim.x + threadIdx.x;
    atomicAdd(&hist[task_key(matches, t)], 1);
}

// one block of 256: exclusive prefix over hist[7744] -> hist & starts; starts[NBUCKET]=total
__global__ __launch_bounds__(256) void scan_kernel(
    int* __restrict__ hist, int* __restrict__ starts) {
    __shared__ int wsum[4];
    const int t = threadIdx.x;
    const int lane = t & 63, w = t >> 6;
    const int per = 32;                 // 256*32 = 8192 >= 7744
    const int base = t * per;
    int s = 0;
    for (int i = 0; i < per; ++i) {
        const int idx = base + i;
        if (idx < NBUCKET) s += hist[idx];
    }
    int pre = s;                        // inclusive wave scan
#pragma unroll
    for (int off = 1; off < 64; off <<= 1) {
        const int x = __shfl_up(pre, off, 64);
        if (lane >= off) pre += x;
    }
    if (lane == 63) wsum[w] = pre;
    __syncthreads();
    int wbase = 0;
#pragma unroll
    for (int k = 0; k < 4; ++k) if (k < w) wbase += wsum[k];
    int run = wbase + pre - s;          // exclusive prefix for this thread's chunk
    for (int i = 0; i < per; ++i) {
        const int idx = base + i;
        if (idx < NBUCKET) {
            const int c = hist[idx];
            hist[idx] = run;
            starts[idx] = run;
            run += c;
        }
    }
    if (t == 255) starts[NBUCKET] = run;
}

__global__ __launch_bounds__(256) void scatter_kernel(
    const int* __restrict__ matches, int* __restrict__ hist,
    int* __restrict__ tasks) {
    const int t = blockIdx.x * blockDim.x + threadIdx.x;
    const int pos = atomicAdd(&hist[task_key(matches, t)], 1);
    tasks[pos] = t;
}

__global__ __launch_bounds__(256) void extract_patch_kernel(
    const float* __restrict__ img1,
    const float* __restrict__ img2,
    const int* __restrict__ matches,
    const int* __restrict__ starts,
    const int* __restrict__ tasks,
    float* __restrict__ out)
{
    __shared__ float tile[TILE * TSTRIDE];   // 64*65*4 = 16640 B

    const int bid = blockIdx.x;
    const int start = starts[bid];
    const int end   = starts[bid + 1];
    if (start == end) return;                // empty bucket: skip tile load

    // decode bucket id: ((b*2+which)*GB + by)*GB + bx
    const int bx = bid % GB;
    const int tmp = bid / GB;
    const int by = tmp % GB;
    const int iw = tmp / GB;                 // b*2+which, 0..15
    const int which = iw & 1;
    const int b = iw >> 1;
    const float* __restrict__ imgb = (which ? img2 : img1) + (size_t)b * HW;

    const int oy = by * BKT - RAD;           // tile origin in image coords
    const int ox = bx * BKT - RAD;

    // ---- stream 64x80... 64 rows x 16 float4 = 1024 units, coalesced ----
    for (int u = threadIdx.x; u < TILE * 16; u += 256) {
        const int tr = u >> 4;
        const int tc = (u & 15) * 4;
        const int gy = oy + tr;
        const int gx = ox + tc;              // (48bx-8)%4==0 -> 16B aligned
        float4 val = make_float4(0.f, 0.f, 0.f, 0.f);
        if ((unsigned)gy < IMG_H) {
            const float* __restrict__ rowp = imgb + gy * IMG_W;
            if ((unsigned)gx <= (unsigned)(IMG_W - 4)) {
                val = *(const float4*)(rowp + gx);
            } else {
                float* vv = (float*)&val;
#pragma unroll
                for (int cc = 0; cc < 4; ++cc) {
                    const int x = gx + cc;
                    if ((unsigned)x < IMG_W) vv[cc] = rowp[x];
                }
            }
        }
        const int la = tr * TSTRIDE + tc;
        tile[la + 0] = val.x; tile[la + 1] = val.y;
        tile[la + 2] = val.z; tile[la + 3] = val.w;
    }
    __syncthreads();

    const int lane  = threadIdx.x & 63;
    const int wslot = threadIdx.x >> 6;

    // lane-constant LDS offsets for the 5 output positions j = lane + 64k
    int ofs[5];
#pragma unroll
    for (int k = 0; k < 5; ++k) {
        const int j = lane + (k << 6);
        ofs[k] = (j % DPATCH) * TSTRIDE + (j / DPATCH);
    }

    // ---- each wave processes bucket tasks round-robin ----
    for (int i = start + wslot; i < end; i += 4) {
        const int t = tasks[i];              // wave-uniform
        const int pair = t >> 1;
        const int wh = t & 1;
        const int mx = matches[pair * 4 + (wh ? 2 : 0)];
        const int my = matches[pair * 4 + (wh ? 3 : 1)];
        // patch element j sits at tile[(my - by*48 + j%17)*65 + (mx - bx*48 + j/17)]
        const int pbase = (my - by * BKT) * TSTRIDE + (mx - bx * BKT);

        float v[5];
        float s = 0.f, q = 0.f;
#pragma unroll
        for (int k = 0; k < 5; ++k) {
            const int j = lane + (k << 6);
            float x = 0.f;
            if (j < NPATCH) x = tile[pbase + ofs[k]];
            v[k] = x;
            s += x;
            q += x * x;
        }
#pragma unroll
        for (int off = 32; off > 0; off >>= 1) {
            s += __shfl_xor(s, off, 64);
            q += __shfl_xor(q, off, 64);
        }
        const float mean = s * (1.0f / 289.0f);
        float var = (q - 289.0f * mean * mean) * (1.0f / 288.0f);
        var = fmaxf(var, 0.0f);
        const float inv = 1.0f / (sqrtf(var) + 1e-4f);

        float* __restrict__ o = out + (size_t)pair * 578 + wh * NPATCH;
#pragma unroll
        for (int k = 0; k < 5; ++k) {
            const int j = lane + (k << 6);
            if (j < NPATCH) {
                __builtin_nontemporal_store((v[k] - mean) * inv, &o[j]);
            }
        }
    }
}

extern "C" void kernel_launch(void* const* d_in, const int* in_sizes, int n_in,
                              void* d_out, int out_size, void* d_ws, size_t ws_size,
                              hipStream_t stream) {
    const float* img1  = (const float*)d_in[0];
    const float* img2  = (const float*)d_in[1];
    const int* matches = (const int*)d_in[2];
    float* out         = (float*)d_out;

    int* w = (int*)d_ws;
    int* hist   = w;            // 7744 used (8192 reserved)
    int* starts = w + 8192;     // 7745 used (8192 reserved)
    int* tasks  = w + 16384;    // 65536

    hipLaunchKernelGGL(zero_hist_kernel, dim3(1), dim3(256), 0, stream, hist);
    hipLaunchKernelGGL(hist_kernel, dim3(NTASK / 256), dim3(256), 0, stream,
                       matches, hist);
    hipLaunchKernelGGL(scan_kernel, dim3(1), dim3(256), 0, stream, hist, starts);
    hipLaunchKernelGGL(scatter_kernel, dim3(NTASK / 256), dim3(256), 0, stream,
                       matches, hist, tasks);
    hipLaunchKernelGGL(extract_patch_kernel, dim3(NBUCKET), dim3(256), 0, stream,
                       img1, img2, matches, starts, tasks, out);
}